// Round 2
// baseline (367.411 us; speedup 1.0000x reference)
//
#include <hip/hip_runtime.h>
#include <hip/hip_bf16.h>
#include <math.h>

// Problem constants
#define BATCH 16
#define L1 32
#define L2 128
#define DEC 512
#define MEM 512
#define TOPN 50
#define NROWS (BATCH * L1 * L2)   // 65536 word rows
#define NBQ (BATCH * L1)          // 512 (b,q) rows

typedef short short8 __attribute__((ext_vector_type(8)));
typedef float f32x16 __attribute__((ext_vector_type(16)));

// ---------------- ws layout (floats) ----------------
#define WS_WP     0          // perm bf16 Wm : 32768 slots x 16B = floats [0,131072)
#define WS_WP2    131072     // perm bf16 Wm2
#define WS_BIAS1  262144
#define WS_BIAS2  270336
#define WS_DOCSC  278528     // doc scores [512] -> end 279040 (~1.07 MB total)

// packed pair via v_cvt_pk_bf16_f32
__device__ __forceinline__ unsigned int pkbf(float a, float b) {
    __hip_bfloat162 h = __float22bfloat162_rn(float2{a, b});
    union { __hip_bfloat162 h; unsigned int u; } c{h};
    return c.u;
}

__device__ __forceinline__ float fast_tanh(float x) {
    return 1.f - 2.f / (__expf(2.f * x) + 1.f);
}

// ============ kernel 0 (merged setup): permute Wm/Wm2 + bias1/bias2 + zero ctx ============
// permute slot s (16B) holds Wm[d][k..k+7] bf16: s = C*1024 + nt*64 + k8*32 + n
//   d = nt*32+n ; k = C*16 + k8*8      (layout HW-verified in R3)
__global__ __launch_bounds__(256) void setup_kernel(
    const float* __restrict__ Wm, const float* __restrict__ Wm2,
    unsigned short* __restrict__ Wp, unsigned short* __restrict__ Wp2,
    const float* __restrict__ dec, const float* __restrict__ topic,
    const float* __restrict__ Wd, const float* __restrict__ Wt,
    const float* __restrict__ Wd2, const float* __restrict__ Wt2,
    float* __restrict__ bias1, float* __restrict__ bias2,
    float* __restrict__ ctx_out)
{
    if (blockIdx.x < 128) {
        int s = blockIdx.x * 256 + threadIdx.x;     // 0..32767
        int C = s >> 10;
        int u = s & 1023;
        int nt = u >> 6, k8 = (u >> 5) & 1, n_in = u & 31;
        int d = nt * 32 + n_in;
        int k = C * 16 + k8 * 8;

        const float* src = Wm + (size_t)d * DEC + k;
        uint4 v;
        v.x = pkbf(src[0], src[1]); v.y = pkbf(src[2], src[3]);
        v.z = pkbf(src[4], src[5]); v.w = pkbf(src[6], src[7]);
        ((uint4*)Wp)[s] = v;

        const float* src2 = Wm2 + (size_t)d * DEC + k;
        uint4 w;
        w.x = pkbf(src2[0], src2[1]); w.y = pkbf(src2[2], src2[3]);
        w.z = pkbf(src2[4], src2[5]); w.w = pkbf(src2[6], src2[7]);
        ((uint4*)Wp2)[s] = w;
    } else if (blockIdx.x < 160) {
        int idx = (blockIdx.x - 128) * 256 + threadIdx.x;   // 8192
        int b = idx >> 9, d = idx & 511;
        float a1 = 0.f, a2 = 0.f;
        const float* db = dec + b * DEC;
        const float* w1 = Wd + (size_t)d * DEC;
        const float* w2 = Wd2 + (size_t)d * DEC;
#pragma unroll 4
        for (int k = 0; k < DEC; ++k) {
            float x = db[k];
            a1 = fmaf(x, w1[k], a1);
            a2 = fmaf(x, w2[k], a2);
        }
        const float* tb = topic + b * TOPN;
        const float* t1 = Wt + (size_t)d * TOPN;
        const float* t2 = Wt2 + (size_t)d * TOPN;
#pragma unroll 2
        for (int t = 0; t < TOPN; ++t) {
            float x = tb[t];
            a1 = fmaf(x, t1[t], a1);
            a2 = fmaf(x, t2[t], a2);
        }
        bias1[idx] = a1;
        bias2[idx] = a2;
    } else {
        // zero ctx accumulator region of d_out (8192 floats)
        int i = (blockIdx.x - 160) * 256 + threadIdx.x;   // 0..1023
        float4 z = {0.f, 0.f, 0.f, 0.f};
        ((float4*)ctx_out)[i * 2] = z;
        ((float4*)ctx_out)[i * 2 + 1] = z;
    }
}

// ============ doc score kernel (R3-verified MFMA kernel, 8 blocks) ============
__global__ __launch_bounds__(256) void score_mfma_kernel(
    const float* __restrict__ X,            // [nrows][512]
    const unsigned short* __restrict__ Wp,  // permuted bf16 weights
    const float* __restrict__ Wv,           // [512]
    const float* __restrict__ bias,         // [16][512]
    float* __restrict__ scores,             // [nrows]
    int bshift)                             // batch = row >> bshift
{
    __shared__ __align__(16) short lsA[256 * 8];
    __shared__ __align__(16) short lsB[2048 * 8];
    __shared__ float red[4][64];

    const int tid = threadIdx.x;
    const int lane = tid & 63;
    const int wid = tid >> 6;
    const int row0 = blockIdx.x * 64;

    const int srow = tid >> 2;
    const int kslot = tid & 3;
    const int sA = ((kslot >> 1) * 2 + (srow >> 5)) * 64 + (kslot & 1) * 32 + (srow & 31);
    const float4* xs4 = (const float4*)(X + (size_t)(row0 + srow) * DEC) + kslot * 2;

    const uint4* bsrc = (const uint4*)Wp + (size_t)wid * 512 + lane;

    f32x16 acc[8];
#pragma unroll
    for (int t = 0; t < 8; ++t)
        acc[t] = (f32x16){0.f,0.f,0.f,0.f, 0.f,0.f,0.f,0.f, 0.f,0.f,0.f,0.f, 0.f,0.f,0.f,0.f};

    const short8* lA = (const short8*)lsA;
    const short8* lB = (const short8*)lsB;

    for (int it = 0; it < 16; ++it) {
        uint4 bv[8];
#pragma unroll
        for (int i = 0; i < 8; ++i) bv[i] = bsrc[i * 64];
        bsrc += 2048;
#pragma unroll
        for (int i = 0; i < 8; ++i)
            *((uint4*)&lsB[((size_t)wid * 512 + i * 64 + lane) * 8]) = bv[i];

        float4 xv0 = xs4[0];
        float4 xv1 = xs4[1];
        xs4 += 8;
        union { unsigned int u[4]; short8 s; } xb;
        xb.u[0] = pkbf(xv0.x, xv0.y); xb.u[1] = pkbf(xv0.z, xv0.w);
        xb.u[2] = pkbf(xv1.x, xv1.y); xb.u[3] = pkbf(xv1.z, xv1.w);
        *((short8*)&lsA[sA * 8]) = xb.s;

        __syncthreads();

#pragma unroll
        for (int c = 0; c < 2; ++c) {
            short8 a0 = lA[(c * 2 + 0) * 64 + lane];
            short8 a1 = lA[(c * 2 + 1) * 64 + lane];
            short8 b0 = lB[c * 1024 + (wid * 4 + 0) * 64 + lane];
            short8 b1 = lB[c * 1024 + (wid * 4 + 1) * 64 + lane];
            short8 b2 = lB[c * 1024 + (wid * 4 + 2) * 64 + lane];
            short8 b3 = lB[c * 1024 + (wid * 4 + 3) * 64 + lane];
            acc[0] = __builtin_amdgcn_mfma_f32_32x32x16_bf16(a0, b0, acc[0], 0, 0, 0);
            acc[1] = __builtin_amdgcn_mfma_f32_32x32x16_bf16(a0, b1, acc[1], 0, 0, 0);
            acc[2] = __builtin_amdgcn_mfma_f32_32x32x16_bf16(a0, b2, acc[2], 0, 0, 0);
            acc[3] = __builtin_amdgcn_mfma_f32_32x32x16_bf16(a0, b3, acc[3], 0, 0, 0);
            acc[4] = __builtin_amdgcn_mfma_f32_32x32x16_bf16(a1, b0, acc[4], 0, 0, 0);
            acc[5] = __builtin_amdgcn_mfma_f32_32x32x16_bf16(a1, b1, acc[5], 0, 0, 0);
            acc[6] = __builtin_amdgcn_mfma_f32_32x32x16_bf16(a1, b2, acc[6], 0, 0, 0);
            acc[7] = __builtin_amdgcn_mfma_f32_32x32x16_bf16(a1, b3, acc[7], 0, 0, 0);
        }
        __syncthreads();
    }

    const int col = lane & 31;
    const int h = lane >> 5;
    float wv[4], bs[2][4];
    const int b0i = (row0) >> bshift;
    const int b1i = (row0 + 32) >> bshift;
#pragma unroll
    for (int nt = 0; nt < 4; ++nt) {
        int d = wid * 128 + nt * 32 + col;
        wv[nt] = Wv[d];
        bs[0][nt] = bias[b0i * DEC + d];
        bs[1][nt] = bias[b1i * DEC + d];
    }

#pragma unroll
    for (int mt = 0; mt < 2; ++mt) {
#pragma unroll
        for (int r = 0; r < 16; ++r) {
            float p = 0.f;
#pragma unroll
            for (int nt = 0; nt < 4; ++nt) {
                float x = acc[mt * 4 + nt][r] + bs[mt][nt];
                p = fmaf(wv[nt], fast_tanh(x), p);
            }
            p += __shfl_xor(p, 16);
            p += __shfl_xor(p, 8);
            p += __shfl_xor(p, 4);
            p += __shfl_xor(p, 2);
            p += __shfl_xor(p, 1);
            if (col == mt * 16 + r) {
                int row_in = (r & 3) + 8 * (r >> 2) + 4 * h;
                red[wid][mt * 32 + row_in] = p;
            }
        }
    }
    __syncthreads();
    if (tid < 64)
        scores[row0 + tid] = red[0][tid] + red[1][tid] + red[2][tid] + red[3][tid];
}

// ============ fused word kernel (R5): full-A-in-LDS, two d-passes, barrier-light ============
// Block = one (b,q): 128 word rows, 512 threads = 8 waves.
// A (128x512 fp32) is staged ONCE into LDS as bf16 (coalesced 1KB/wave-instr streams),
// pipelined 2-deep at K=128 superchunk granularity (4 lgkm-only barriers total).
// Wave tile = 64 rows x 64 d: wr = wid&1 (row half), wd = wid>>1 (d group).
// Two d-passes (d 0..255, 256..511) reuse the staged A; acc = 4 x f32x16 = 64 regs.
// Compute loops are barrier-free with rolling 2-deep B prefetch from L2.
// LDS A layout: plane k8g (0..63, 8 k's each) stride 2064B (16B pad), row*16 + half*8.
__global__ __launch_bounds__(512) void fused_word_kernel(
    const float* __restrict__ X,            // word_memory [65536][512]
    const unsigned short* __restrict__ Wp,  // permuted bf16 Wm
    const float* __restrict__ Wv,           // [512]
    const float* __restrict__ bias1,        // [16][512]
    const float* __restrict__ doc_scores,   // [512]
    const int* __restrict__ doc_mask,       // [512]
    const int* __restrict__ word_mask,      // [65536]
    float* __restrict__ rescaled_out,       // d_out + 8192
    float* __restrict__ ctx_out)            // d_out [16][512], pre-zeroed, atomic
{
    __shared__ __align__(16) char lsA[64 * 2064];   // 132096 B: full A tile, bf16, padded planes
    __shared__ float red[8][128];
    __shared__ float sS[128];
    __shared__ float rmax2[2], rsum2[2];
    __shared__ float s_dattn;
    __shared__ __align__(16) float4 part[3 * 128];

    const int tid = threadIdx.x;
    const int lane = tid & 63;
    const int wid = tid >> 6;          // 0..7
    const int wr = wid & 1;            // row half (rows wr*64 .. +63)
    const int wd = wid >> 1;           // d group (d = pass*256 + wd*64 .. +63)
    const int bq = blockIdx.x;         // 0..511
    const int r0 = bq * L2;            // first word row
    const int b = bq >> 5;
    const int q = bq & 31;
    const int col = lane & 31;
    const int h = lane >> 5;

    // ---- staging maps ----
    // load: thread covers f4-column (tid&31) of superchunk, rows (tid>>5) + 16*i
    const float4* Xs = (const float4*)X + (size_t)(r0 + (tid >> 5)) * 128 + (tid & 31);
    // LDS write base: plane = ks*16 + (tid&31)>>1, row=(tid>>5)+16i, half = tid&1
    char* const wbase = lsA + (((tid & 31) >> 1) * 2064) + ((tid >> 5) << 4) + ((tid & 1) << 3);

#define ISSUE(dst, ks) { _Pragma("unroll") \
    for (int i = 0; i < 8; ++i) dst[i] = Xs[(size_t)(i * 16) * 128 + (ks) * 32]; }

#define WRITEA(src, ks) { char* wp = wbase + (ks) * 16 * 2064; _Pragma("unroll") \
    for (int i = 0; i < 8; ++i) { uint2 w; \
        w.x = pkbf(src[i].x, src[i].y); w.y = pkbf(src[i].z, src[i].w); \
        *(uint2*)(wp + i * 256) = w; } }

#define LGKMBAR { asm volatile("s_waitcnt lgkmcnt(0)" ::: "memory"); \
                  __builtin_amdgcn_s_barrier(); asm volatile("" ::: "memory"); }

    // ---- B addressing (permuted layout, 16B slots) ----
    const uint4* Bp = (const uint4*)Wp;
    const size_t bB = (size_t)wd * 128 + lane;
#define BOFFC(t, nt) ((size_t)(((t) & 31)) * 1024 + ((((t) >> 5) & 1)) * 512 + bB + (nt) * 64)

    // ---- A fragment addressing (from LDS) ----
    const char* const aP = lsA + (lane >> 5) * 2064 + ((wr * 64) + (lane & 31)) * 16;
#define MFMA(a, bb, c) __builtin_amdgcn_mfma_f32_32x32x16_bf16(a, bb, c, 0, 0, 0)

    f32x16 acc[4];   // [mt*2 + nt]
#pragma unroll
    for (int t = 0; t < 4; ++t)
        acc[t] = (f32x16){0.f,0.f,0.f,0.f, 0.f,0.f,0.f,0.f, 0.f,0.f,0.f,0.f, 0.f,0.f,0.f,0.f};

    uint4 ub[2][2];

#define CHUNK(t) { \
    union { uint4 u; short8 s8; } c0{ub[(t) & 1][0]}, c1{ub[(t) & 1][1]}; \
    ub[(t) & 1][0] = Bp[BOFFC(((t) + 2) & 63, 0)]; \
    ub[(t) & 1][1] = Bp[BOFFC(((t) + 2) & 63, 1)]; \
    short8 a0 = *(const short8*)(aP + ((t) & 31) * 4128); \
    short8 a1 = *(const short8*)(aP + ((t) & 31) * 4128 + 512); \
    acc[0] = MFMA(a0, c0.s8, acc[0]); \
    acc[1] = MFMA(a0, c1.s8, acc[1]); \
    acc[2] = MFMA(a1, c0.s8, acc[2]); \
    acc[3] = MFMA(a1, c1.s8, acc[3]); }

#define CHUNK8(base) { CHUNK((base)+0) CHUNK((base)+1) CHUNK((base)+2) CHUNK((base)+3) \
                       CHUNK((base)+4) CHUNK((base)+5) CHUNK((base)+6) CHUNK((base)+7) }

#define EPILOGUE(p) { \
    int d0 = (p) * 256 + wd * 64 + col; \
    float wv0 = Wv[d0], wv1 = Wv[d0 + 32]; \
    float bs0 = bias1[b * DEC + d0], bs1 = bias1[b * DEC + d0 + 32]; \
    _Pragma("unroll") for (int mt = 0; mt < 2; ++mt) { \
      _Pragma("unroll") for (int r = 0; r < 16; ++r) { \
        float val = fmaf(wv0, fast_tanh(acc[mt * 2 + 0][r] + bs0), \
                         wv1 * fast_tanh(acc[mt * 2 + 1][r] + bs1)); \
        val += __shfl_xor(val, 16); val += __shfl_xor(val, 8); \
        val += __shfl_xor(val, 4);  val += __shfl_xor(val, 2); \
        val += __shfl_xor(val, 1); \
        if (col == r) red[(p) * 4 + wd][wr * 64 + mt * 32 + ((r & 3) + 8 * (r >> 2) + 4 * h)] = val; \
      } } }

    // ---- prologue: issue superchunks 0,1 (2-deep, 128B/thread in flight) ----
    float4 vA[8], vB[8];
    ISSUE(vA, 0);
    ISSUE(vB, 1);

    // ---- doc softmax for this block's (b,q): one scalar (overlaps load latency) ----
    if (tid < 32) {
        int di = b * 32 + tid;
        float dsv = doc_scores[di];
        if (doc_mask[di] == 0) dsv = -INFINITY;
        float mx = dsv;
#pragma unroll
        for (int o = 1; o <= 16; o <<= 1) mx = fmaxf(mx, __shfl_xor(mx, o));
        float e = __expf(dsv - mx);
        float sum = e;
#pragma unroll
        for (int o = 1; o <= 16; o <<= 1) sum += __shfl_xor(sum, o);
        if (tid == q) s_dattn = e / sum;
    }

    // ---- pass 1 (d 0..255), staging interleaved per K=128 superchunk ----
    WRITEA(vA, 0);
    ub[0][0] = Bp[BOFFC(0, 0)];
    ub[0][1] = Bp[BOFFC(0, 1)];
    ub[1][0] = Bp[BOFFC(1, 0)];
    ub[1][1] = Bp[BOFFC(1, 1)];
    LGKMBAR;
    ISSUE(vA, 2);
    CHUNK8(0);
    WRITEA(vB, 1);
    LGKMBAR;
    ISSUE(vB, 3);
    CHUNK8(8);
    WRITEA(vA, 2);
    LGKMBAR;
    CHUNK8(16);
    WRITEA(vB, 3);
    LGKMBAR;
    CHUNK8(24);          // rolling prefetch reaches t=32,33 (pass-2 first B frags)

    EPILOGUE(0);         // frees acc; pass-2 B loads fly under this VALU work

#pragma unroll
    for (int t = 0; t < 4; ++t)
        acc[t] = (f32x16){0.f,0.f,0.f,0.f, 0.f,0.f,0.f,0.f, 0.f,0.f,0.f,0.f, 0.f,0.f,0.f,0.f};

    // ---- pass 2 (d 256..511): barrier-free, A from LDS ----
#pragma unroll 2
    for (int j = 0; j < 16; ++j) {
        const int c0 = 2 * j, c1 = 2 * j + 1;
        {
            union { uint4 u; short8 s8; } d00{ub[0][0]}, d01{ub[0][1]};
            int tt = (32 + c0 + 2) & 63;
            size_t off = (size_t)(tt & 31) * 1024 + ((tt >> 5) & 1) * 512 + bB;
            ub[0][0] = Bp[off];
            ub[0][1] = Bp[off + 64];
            short8 a0 = *(const short8*)(aP + c0 * 4128);
            short8 a1 = *(const short8*)(aP + c0 * 4128 + 512);
            acc[0] = MFMA(a0, d00.s8, acc[0]);
            acc[1] = MFMA(a0, d01.s8, acc[1]);
            acc[2] = MFMA(a1, d00.s8, acc[2]);
            acc[3] = MFMA(a1, d01.s8, acc[3]);
        }
        {
            union { uint4 u; short8 s8; } d10{ub[1][0]}, d11{ub[1][1]};
            int tt = (32 + c1 + 2) & 63;
            size_t off = (size_t)(tt & 31) * 1024 + ((tt >> 5) & 1) * 512 + bB;
            ub[1][0] = Bp[off];
            ub[1][1] = Bp[off + 64];
            short8 a0 = *(const short8*)(aP + c1 * 4128);
            short8 a1 = *(const short8*)(aP + c1 * 4128 + 512);
            acc[0] = MFMA(a0, d10.s8, acc[0]);
            acc[1] = MFMA(a0, d11.s8, acc[1]);
            acc[2] = MFMA(a1, d10.s8, acc[2]);
            acc[3] = MFMA(a1, d11.s8, acc[3]);
        }
    }

    EPILOGUE(1);

    __syncthreads();

    // ---- block softmax over 128 words (threads 0..127) ----
    float e = 0.f, sv = 0.f;
    if (tid < 128) {
        sv = red[0][tid] + red[1][tid] + red[2][tid] + red[3][tid]
           + red[4][tid] + red[5][tid] + red[6][tid] + red[7][tid];
        if (word_mask[r0 + tid] == 0) sv = -INFINITY;
        float mx = sv;
#pragma unroll
        for (int o = 1; o <= 32; o <<= 1) mx = fmaxf(mx, __shfl_xor(mx, o));
        if (lane == 0) rmax2[wid] = mx;
    }
    __syncthreads();
    if (tid < 128) {
        float mx = fmaxf(rmax2[0], rmax2[1]);
        e = __expf(sv - mx);
        float sum = e;
#pragma unroll
        for (int o = 1; o <= 32; o <<= 1) sum += __shfl_xor(sum, o);
        if (lane == 0) rsum2[wid] = sum;
    }
    __syncthreads();
    if (tid < 128) {
        float sum = rsum2[0] + rsum2[1];
        float resc = s_dattn * (e / sum);
        sS[tid] = resc;
        rescaled_out[r0 + tid] = resc;
    }
    __syncthreads();

    // ---- context partial (fp32 X re-read, L2-hot) + atomic accumulate ----
    const int hh = tid >> 7;          // 0..3: w-group of 32
    const int m4 = tid & 127;         // float4 index in m
    const float4* Xr = (const float4*)X + (size_t)r0 * 128 + (size_t)hh * 32 * 128 + m4;
    float4 a = {0.f, 0.f, 0.f, 0.f};
#pragma unroll 8
    for (int i = 0; i < 32; ++i) {
        float rr = sS[hh * 32 + i];
        float4 v = Xr[(size_t)i * 128];
        a.x = fmaf(rr, v.x, a.x);
        a.y = fmaf(rr, v.y, a.y);
        a.z = fmaf(rr, v.z, a.z);
        a.w = fmaf(rr, v.w, a.w);
    }
    if (hh) part[(hh - 1) * 128 + m4] = a;
    __syncthreads();
    if (hh == 0) {
        float4 p0 = part[m4], p1 = part[128 + m4], p2 = part[256 + m4];
        a.x += p0.x + p1.x + p2.x;
        a.y += p0.y + p1.y + p2.y;
        a.z += p0.z + p1.z + p2.z;
        a.w += p0.w + p1.w + p2.w;
        float* dst = ctx_out + (size_t)b * MEM + m4 * 4;
        atomicAdd(dst + 0, a.x);
        atomicAdd(dst + 1, a.y);
        atomicAdd(dst + 2, a.z);
        atomicAdd(dst + 3, a.w);
    }
}

extern "C" void kernel_launch(void* const* d_in, const int* in_sizes, int n_in,
                              void* d_out, int out_size, void* d_ws, size_t ws_size,
                              hipStream_t stream) {
    const float* decoder_state = (const float*)d_in[0];
    const float* doc_memory    = (const float*)d_in[1];
    const float* word_memory   = (const float*)d_in[2];
    const float* topic_dist    = (const float*)d_in[3];
    const int*   doc_mask      = (const int*)d_in[4];
    const int*   word_mask     = (const int*)d_in[5];
    const float* Wv  = (const float*)d_in[6];
    const float* Wd  = (const float*)d_in[7];
    const float* Wt  = (const float*)d_in[8];
    const float* Wm  = (const float*)d_in[9];
    const float* Wv2 = (const float*)d_in[10];
    const float* Wd2 = (const float*)d_in[11];
    const float* Wt2 = (const float*)d_in[12];
    const float* Wm2 = (const float*)d_in[13];

    float* ws = (float*)d_ws;
    unsigned short* Wp  = (unsigned short*)(ws + WS_WP);
    unsigned short* Wp2 = (unsigned short*)(ws + WS_WP2);
    float* bias1       = ws + WS_BIAS1;
    float* bias2       = ws + WS_BIAS2;
    float* doc_scores  = ws + WS_DOCSC;

    float* ctx_out      = (float*)d_out;                 // [16][512]
    float* rescaled_out = (float*)d_out + BATCH * MEM;   // [16][32][128]

    setup_kernel<<<164, 256, 0, stream>>>(Wm, Wm2, Wp, Wp2,
                                          decoder_state, topic_dist,
                                          Wd, Wt, Wd2, Wt2, bias1, bias2, ctx_out);
    score_mfma_kernel<<<NBQ / 64, 256, 0, stream>>>(doc_memory, Wp2, Wv2, bias2, doc_scores, 5);
    fused_word_kernel<<<NBQ, 512, 0, stream>>>(word_memory, Wp, Wv, bias1,
                                               doc_scores, doc_mask, word_mask,
                                               rescaled_out, ctx_out);
}

// Round 3
// 341.962 us; speedup vs baseline: 1.0744x; 1.0744x over previous
//
#include <hip/hip_runtime.h>
#include <hip/hip_bf16.h>
#include <math.h>

// Problem constants
#define BATCH 16
#define L1 32
#define L2 128
#define DEC 512
#define MEM 512
#define TOPN 50
#define NROWS (BATCH * L1 * L2)   // 65536 word rows
#define NBQ (BATCH * L1)          // 512 (b,q) rows

typedef short short8 __attribute__((ext_vector_type(8)));
typedef float f32x16 __attribute__((ext_vector_type(16)));

// ---------------- ws layout (floats) ----------------
#define WS_WP     0          // perm bf16 Wm : 32768 slots x 16B = floats [0,131072)
#define WS_WP2    131072     // perm bf16 Wm2
#define WS_BIAS1  262144
#define WS_BIAS2  270336
#define WS_DOCSC  278528     // doc scores [512] -> end 279040 (~1.07 MB total)

// packed pair via v_cvt_pk_bf16_f32
__device__ __forceinline__ unsigned int pkbf(float a, float b) {
    __hip_bfloat162 h = __float22bfloat162_rn(float2{a, b});
    union { __hip_bfloat162 h; unsigned int u; } c{h};
    return c.u;
}

__device__ __forceinline__ float fast_tanh(float x) {
    return 1.f - 2.f / (__expf(2.f * x) + 1.f);
}

// ============ kernel 0 (setup): permute Wm/Wm2 + bias via wave-per-output + zero ctx ============
// permute slot s (16B) holds Wm[d][k..k+7] bf16: s = C*1024 + nt*64 + k8*32 + n
//   d = nt*32+n ; k = C*16 + k8*8      (layout HW-verified in R3)
// bias: one output (mat,b,d) per WAVE: coalesced float4 row reads + 64-lane shuffle reduce.
__global__ __launch_bounds__(256) void setup_kernel(
    const float* __restrict__ Wm, const float* __restrict__ Wm2,
    unsigned short* __restrict__ Wp, unsigned short* __restrict__ Wp2,
    const float* __restrict__ dec, const float* __restrict__ topic,
    const float* __restrict__ Wd, const float* __restrict__ Wt,
    const float* __restrict__ Wd2, const float* __restrict__ Wt2,
    float* __restrict__ bias1, float* __restrict__ bias2,
    float* __restrict__ ctx_out)
{
    const int bid = blockIdx.x;
    const int tid = threadIdx.x;
    if (bid < 128) {
        int s = bid * 256 + tid;                    // 0..32767
        int C = s >> 10;
        int u = s & 1023;
        int nt = u >> 6, k8 = (u >> 5) & 1, n_in = u & 31;
        int d = nt * 32 + n_in;
        int k = C * 16 + k8 * 8;

        const float4* src = (const float4*)(Wm + (size_t)d * DEC + k);
        float4 v0 = src[0], v1 = src[1];
        uint4 v;
        v.x = pkbf(v0.x, v0.y); v.y = pkbf(v0.z, v0.w);
        v.z = pkbf(v1.x, v1.y); v.w = pkbf(v1.z, v1.w);
        ((uint4*)Wp)[s] = v;

        const float4* src2 = (const float4*)(Wm2 + (size_t)d * DEC + k);
        float4 w0 = src2[0], w1 = src2[1];
        uint4 w;
        w.x = pkbf(w0.x, w0.y); w.y = pkbf(w0.z, w0.w);
        w.z = pkbf(w1.x, w1.y); w.w = pkbf(w1.z, w1.w);
        ((uint4*)Wp2)[s] = w;
    } else if (bid < 128 + 4096) {
        // one bias output per wave: gw in [0,16384)
        int gw = (bid - 128) * 4 + (tid >> 6);
        int lane = tid & 63;
        int mat = gw >> 13;                 // 0: bias1 (Wd,Wt), 1: bias2 (Wd2,Wt2)
        int rem = gw & 8191;
        int bb = rem >> 9;                  // 0..15
        int d = rem & 511;                  // 0..511

        const float* wrow = (mat ? Wd2 : Wd) + (size_t)d * DEC;
        const float* drow = dec + (size_t)bb * DEC;
        float4 a0 = ((const float4*)wrow)[lane * 2];
        float4 a1 = ((const float4*)wrow)[lane * 2 + 1];
        float4 x0 = ((const float4*)drow)[lane * 2];
        float4 x1 = ((const float4*)drow)[lane * 2 + 1];
        float acc = a0.x * x0.x;
        acc = fmaf(a0.y, x0.y, acc);
        acc = fmaf(a0.z, x0.z, acc);
        acc = fmaf(a0.w, x0.w, acc);
        acc = fmaf(a1.x, x1.x, acc);
        acc = fmaf(a1.y, x1.y, acc);
        acc = fmaf(a1.z, x1.z, acc);
        acc = fmaf(a1.w, x1.w, acc);
        const float* trow = (mat ? Wt2 : Wt) + (size_t)d * TOPN;
        if (lane < TOPN) acc = fmaf(trow[lane], topic[bb * TOPN + lane], acc);
#pragma unroll
        for (int o = 1; o <= 32; o <<= 1) acc += __shfl_xor(acc, o);
        if (lane == 0) (mat ? bias2 : bias1)[bb * DEC + d] = acc;
    } else {
        // zero ctx accumulator region of d_out (8192 floats), 4 blocks
        int i = (bid - (128 + 4096)) * 256 + tid;   // 0..1023
        float4 z = {0.f, 0.f, 0.f, 0.f};
        ((float4*)ctx_out)[i * 2] = z;
        ((float4*)ctx_out)[i * 2 + 1] = z;
    }
}

// ============ score_all kernel: word + doc scores in one grid ============
// 64 rows/block, 256 threads (4 waves), 2 blocks/CU (LDS 66KB).
// A staged ONCE into LDS (row-major bf16, stride 520 shorts = 1040B: conflict-free
// ds_writes, ~4-way b128 reads). ONE barrier for staging, then two d-passes
// (d 0..255, 256..511), each: 32 K-steps of {2 ds_read_b128, 2 L2 B-loads
// (8-deep reg ring), 4 MFMA}. acc[4] = 64 AGPR -> 2 waves/SIMD, 8 independent
// waves/CU streaming (TLP hides HBM/L2 latency; no per-step barriers at all).
// B slot addressing (verified layout): slot(d-chunk D, k-step t, lane) = t*1024 + D*64 + lane.
__global__ __launch_bounds__(256, 2) void score_all_kernel(
    const float* __restrict__ Xw,            // word_memory [65536][512]
    const float* __restrict__ Xd,            // doc_memory [512][512]
    const unsigned short* __restrict__ Wp,   // permuted bf16 Wm
    const unsigned short* __restrict__ Wp2,  // permuted bf16 Wm2
    const float* __restrict__ Wv, const float* __restrict__ Wv2,
    const float* __restrict__ bias1, const float* __restrict__ bias2,
    float* __restrict__ word_scores,         // aliases rescaled_out region
    float* __restrict__ doc_scores)
{
    __shared__ __align__(16) char lsA[64 * 1040];   // 66560 B
    __shared__ float red[4][64];

    const int bid = blockIdx.x;
    const int tid = threadIdx.x;
    const bool isdoc = (bid >= 1024);

    const float* X;
    const unsigned short* Wpp;
    const float* Wvp;
    const float* bias;
    float* outp;
    int r0, bshift;
    if (isdoc) { X = Xd; Wpp = Wp2; Wvp = Wv2; bias = bias2; outp = doc_scores; r0 = (bid - 1024) * 64; bshift = 5; }
    else       { X = Xw; Wpp = Wp;  Wvp = Wv;  bias = bias1; outp = word_scores; r0 = bid * 64; bshift = 12; }

    // ---- stage A: 64 rows x 512 k fp32 -> bf16 LDS, coalesced 1KB/wave-instr ----
    {
        const int kf4 = tid & 127;
        const int rb0 = tid >> 7;
        const float4* Xs = (const float4*)X + (size_t)r0 * 128 + kf4;
        float4 va[8], vb[8];
#pragma unroll
        for (int i = 0; i < 8; ++i) va[i] = Xs[(size_t)(2 * i + rb0) * 128];
#pragma unroll
        for (int blk = 0; blk < 4; ++blk) {
            float4* cur = (blk & 1) ? vb : va;
            float4* nxt = (blk & 1) ? va : vb;
            if (blk < 3) {
#pragma unroll
                for (int i = 0; i < 8; ++i)
                    nxt[i] = Xs[(size_t)(2 * (8 * (blk + 1) + i) + rb0) * 128];
            }
#pragma unroll
            for (int i = 0; i < 8; ++i) {
                int row = 2 * (8 * blk + i) + rb0;
                uint2 w;
                w.x = pkbf(cur[i].x, cur[i].y);
                w.y = pkbf(cur[i].z, cur[i].w);
                *(uint2*)(lsA + (size_t)row * 1040 + kf4 * 8) = w;
            }
        }
    }
    __syncthreads();

    // ---- main: per-wave independent, no barriers ----
    const int lane = tid & 63;
    const int wid = tid >> 6;          // 0..3: d-slice within pass
    const int col = lane & 31;
    const int h = lane >> 5;

    const char* aB0 = lsA + (size_t)col * 1040 + h * 16;   // rg 0 rows 0..31
    const char* aB1 = aB0 + 32 * 1040;                     // rg 1 rows 32..63

    const uint4* Bq = (const uint4*)Wpp;
    const int bBase = wid * 128 + lane;
#define BOFF(s) ((size_t)((s) & 31) * 1024 + (size_t)((s) >> 5) * 512 + bBase)
#define MFMA(a, bb, c) __builtin_amdgcn_mfma_f32_32x32x16_bf16(a, bb, c, 0, 0, 0)

    uint4 rbf[8][2];
#pragma unroll
    for (int i = 0; i < 8; ++i) { rbf[i][0] = Bq[BOFF(i)]; rbf[i][1] = Bq[BOFF(i) + 64]; }

    float preg0 = 0.f, preg1 = 0.f;
    const int b0i = (r0) >> bshift;
    const int b1i = (r0 + 32) >> bshift;

#pragma unroll
    for (int P = 0; P < 2; ++P) {
        f32x16 acc0, acc1, acc2, acc3;
        acc0 = acc1 = acc2 = acc3 =
            (f32x16){0.f,0.f,0.f,0.f, 0.f,0.f,0.f,0.f, 0.f,0.f,0.f,0.f, 0.f,0.f,0.f,0.f};
#pragma unroll
        for (int t = 0; t < 32; ++t) {
            const int s = P * 32 + t;
            short8 a0 = *(const short8*)(aB0 + t * 32);
            short8 a1 = *(const short8*)(aB1 + t * 32);
            union { uint4 u; short8 s8; } c0{rbf[s & 7][0]}, c1{rbf[s & 7][1]};
            if (s < 56) { rbf[s & 7][0] = Bq[BOFF(s + 8)]; rbf[s & 7][1] = Bq[BOFF(s + 8) + 64]; }
            acc0 = MFMA(a0, c0.s8, acc0);
            acc1 = MFMA(a0, c1.s8, acc1);
            acc2 = MFMA(a1, c0.s8, acc2);
            acc3 = MFMA(a1, c1.s8, acc3);
        }
        // epilogue for this pass: tanh + Wv partial, accumulate per-lane row partials
        const int d0 = P * 256 + wid * 64 + col;
        const float wv0 = Wvp[d0], wv1 = Wvp[d0 + 32];
        {
            const float bs0 = bias[b0i * DEC + d0], bs1 = bias[b0i * DEC + d0 + 32];
#pragma unroll
            for (int r = 0; r < 16; ++r) {
                float val = fmaf(wv0, fast_tanh(acc0[r] + bs0),
                                 wv1 * fast_tanh(acc1[r] + bs1));
                val += __shfl_xor(val, 16);
                val += __shfl_xor(val, 8);
                val += __shfl_xor(val, 4);
                val += __shfl_xor(val, 2);
                val += __shfl_xor(val, 1);
                preg0 += (col == r) ? val : 0.f;
            }
        }
        {
            const float bs0 = bias[b1i * DEC + d0], bs1 = bias[b1i * DEC + d0 + 32];
#pragma unroll
            for (int r = 0; r < 16; ++r) {
                float val = fmaf(wv0, fast_tanh(acc2[r] + bs0),
                                 wv1 * fast_tanh(acc3[r] + bs1));
                val += __shfl_xor(val, 16);
                val += __shfl_xor(val, 8);
                val += __shfl_xor(val, 4);
                val += __shfl_xor(val, 2);
                val += __shfl_xor(val, 1);
                preg1 += (col == r) ? val : 0.f;
            }
        }
    }

    // red write: lanes with col<16 each hold one row per rg (row_in bijective over (col<16, h))
    const int rowin = (col & 3) + 8 * (col >> 2) + 4 * h;
    if (col < 16) {
        red[wid][rowin] = preg0;
        red[wid][32 + rowin] = preg1;
    }
    __syncthreads();
    if (tid < 64)
        outp[r0 + tid] = red[0][tid] + red[1][tid] + red[2][tid] + red[3][tid];
}

// ============ combine kernel: doc softmax + word softmax + rescale + ctx ============
// 512 blocks (one per (b,q)), 256 threads, high occupancy (4 blocks/CU).
// Reads word scores from the rescaled region, overwrites in-place with resc.
__global__ __launch_bounds__(256, 4) void combine_kernel(
    const float* __restrict__ X,             // word_memory [65536][512]
    const float* __restrict__ doc_scores,    // [512]
    const int* __restrict__ doc_mask,        // [512]
    const int* __restrict__ word_mask,       // [65536]
    float* __restrict__ rescaled_out,        // scores in, resc out (in-place)
    float* __restrict__ ctx_out)             // [16][512], pre-zeroed, atomic
{
    __shared__ float sS[128];
    __shared__ float rmax2[2], rsum2[2];
    __shared__ float s_dattn;
    __shared__ __align__(16) float4 part[128];

    const int tid = threadIdx.x;
    const int lane = tid & 63;
    const int wid = tid >> 6;
    const int bq = blockIdx.x;
    const int r0 = bq * L2;
    const int b = bq >> 5;
    const int q = bq & 31;

    // ---- doc softmax for this (b,q) ----
    if (tid < 32) {
        int di = b * 32 + tid;
        float dsv = doc_scores[di];
        if (doc_mask[di] == 0) dsv = -INFINITY;
        float mx = dsv;
#pragma unroll
        for (int o = 1; o <= 16; o <<= 1) mx = fmaxf(mx, __shfl_xor(mx, o));
        float e = __expf(dsv - mx);
        float sum = e;
#pragma unroll
        for (int o = 1; o <= 16; o <<= 1) sum += __shfl_xor(sum, o);
        if (tid == q) s_dattn = e / sum;
    }

    // ---- word softmax over 128 rows (threads 0..127) ----
    float e = 0.f, sv = 0.f;
    if (tid < 128) {
        sv = rescaled_out[r0 + tid];
        if (word_mask[r0 + tid] == 0) sv = -INFINITY;
        float mx = sv;
#pragma unroll
        for (int o = 1; o <= 32; o <<= 1) mx = fmaxf(mx, __shfl_xor(mx, o));
        if (lane == 0) rmax2[wid] = mx;
    }
    __syncthreads();
    if (tid < 128) {
        float mx = fmaxf(rmax2[0], rmax2[1]);
        e = __expf(sv - mx);
        float sum = e;
#pragma unroll
        for (int o = 1; o <= 32; o <<= 1) sum += __shfl_xor(sum, o);
        if (lane == 0) rsum2[wid] = sum;
    }
    __syncthreads();
    if (tid < 128) {
        float sum = rsum2[0] + rsum2[1];
        float resc = s_dattn * (e / sum);
        sS[tid] = resc;
        rescaled_out[r0 + tid] = resc;
    }
    __syncthreads();

    // ---- context partial (X re-read, L3-resident) + atomic accumulate ----
    const int hh = tid >> 7;          // 0..1: 64 rows each
    const int m4 = tid & 127;         // float4 index in m
    const float4* Xr = (const float4*)X + (size_t)(r0 + hh * 64) * 128 + m4;
    float4 a = {0.f, 0.f, 0.f, 0.f};
#pragma unroll 8
    for (int i = 0; i < 64; ++i) {
        float rr = sS[hh * 64 + i];
        float4 v = Xr[(size_t)i * 128];
        a.x = fmaf(rr, v.x, a.x);
        a.y = fmaf(rr, v.y, a.y);
        a.z = fmaf(rr, v.z, a.z);
        a.w = fmaf(rr, v.w, a.w);
    }
    if (hh) part[m4] = a;
    __syncthreads();
    if (hh == 0) {
        float4 p0 = part[m4];
        a.x += p0.x; a.y += p0.y; a.z += p0.z; a.w += p0.w;
        float* dst = ctx_out + (size_t)b * MEM + m4 * 4;
        atomicAdd(dst + 0, a.x);
        atomicAdd(dst + 1, a.y);
        atomicAdd(dst + 2, a.z);
        atomicAdd(dst + 3, a.w);
    }
}

extern "C" void kernel_launch(void* const* d_in, const int* in_sizes, int n_in,
                              void* d_out, int out_size, void* d_ws, size_t ws_size,
                              hipStream_t stream) {
    const float* decoder_state = (const float*)d_in[0];
    const float* doc_memory    = (const float*)d_in[1];
    const float* word_memory   = (const float*)d_in[2];
    const float* topic_dist    = (const float*)d_in[3];
    const int*   doc_mask      = (const int*)d_in[4];
    const int*   word_mask     = (const int*)d_in[5];
    const float* Wv  = (const float*)d_in[6];
    const float* Wd  = (const float*)d_in[7];
    const float* Wt  = (const float*)d_in[8];
    const float* Wm  = (const float*)d_in[9];
    const float* Wv2 = (const float*)d_in[10];
    const float* Wd2 = (const float*)d_in[11];
    const float* Wt2 = (const float*)d_in[12];
    const float* Wm2 = (const float*)d_in[13];

    float* ws = (float*)d_ws;
    unsigned short* Wp  = (unsigned short*)(ws + WS_WP);
    unsigned short* Wp2 = (unsigned short*)(ws + WS_WP2);
    float* bias1       = ws + WS_BIAS1;
    float* bias2       = ws + WS_BIAS2;
    float* doc_scores  = ws + WS_DOCSC;

    float* ctx_out      = (float*)d_out;                 // [16][512]
    float* rescaled_out = (float*)d_out + BATCH * MEM;   // [16][32][128] (scores scratch, then resc)

    setup_kernel<<<128 + 4096 + 4, 256, 0, stream>>>(Wm, Wm2, Wp, Wp2,
                                                     decoder_state, topic_dist,
                                                     Wd, Wt, Wd2, Wt2, bias1, bias2, ctx_out);
    score_all_kernel<<<1024 + 8, 256, 0, stream>>>(word_memory, doc_memory, Wp, Wp2,
                                                   Wv, Wv2, bias1, bias2,
                                                   rescaled_out, doc_scores);
    combine_kernel<<<NBQ, 256, 0, stream>>>(word_memory, doc_scores, doc_mask, word_mask,
                                            rescaled_out, ctx_out);
}

// Round 4
// 315.918 us; speedup vs baseline: 1.1630x; 1.0824x over previous
//
#include <hip/hip_runtime.h>
#include <hip/hip_bf16.h>
#include <math.h>

// Problem constants
#define BATCH 16
#define L1 32
#define L2 128
#define DEC 512
#define MEM 512
#define TOPN 50
#define NROWS (BATCH * L1 * L2)   // 65536 word rows
#define NBQ (BATCH * L1)          // 512 (b,q) rows

typedef short short8 __attribute__((ext_vector_type(8)));
typedef float f32x16 __attribute__((ext_vector_type(16)));

// ---------------- ws layout (floats) ----------------
#define WS_WP     0          // perm bf16 Wm : 32768 slots x 16B = floats [0,131072)
#define WS_WP2    131072     // perm bf16 Wm2
#define WS_BIAS1  262144
#define WS_BIAS2  270336
#define WS_DOCSC  278528     // doc scores [512] -> end 279040 (~1.07 MB total)

// packed pair via v_cvt_pk_bf16_f32
__device__ __forceinline__ unsigned int pkbf(float a, float b) {
    __hip_bfloat162 h = __float22bfloat162_rn(float2{a, b});
    union { __hip_bfloat162 h; unsigned int u; } c{h};
    return c.u;
}

__device__ __forceinline__ float fast_tanh(float x) {
    return 1.f - 2.f / (__expf(2.f * x) + 1.f);
}

// ============ kernel 0 (setup): permute Wm/Wm2 + bias via wave-per-output + zero ctx ============
// permute slot s (16B) holds Wm[d][k..k+7] bf16: s = C*1024 + nt*64 + k8*32 + n
//   d = nt*32+n ; k = C*16 + k8*8      (layout HW-verified)
__global__ __launch_bounds__(256) void setup_kernel(
    const float* __restrict__ Wm, const float* __restrict__ Wm2,
    unsigned short* __restrict__ Wp, unsigned short* __restrict__ Wp2,
    const float* __restrict__ dec, const float* __restrict__ topic,
    const float* __restrict__ Wd, const float* __restrict__ Wt,
    const float* __restrict__ Wd2, const float* __restrict__ Wt2,
    float* __restrict__ bias1, float* __restrict__ bias2,
    float* __restrict__ ctx_out)
{
    const int bid = blockIdx.x;
    const int tid = threadIdx.x;
    if (bid < 128) {
        int s = bid * 256 + tid;                    // 0..32767
        int C = s >> 10;
        int u = s & 1023;
        int nt = u >> 6, k8 = (u >> 5) & 1, n_in = u & 31;
        int d = nt * 32 + n_in;
        int k = C * 16 + k8 * 8;

        const float4* src = (const float4*)(Wm + (size_t)d * DEC + k);
        float4 v0 = src[0], v1 = src[1];
        uint4 v;
        v.x = pkbf(v0.x, v0.y); v.y = pkbf(v0.z, v0.w);
        v.z = pkbf(v1.x, v1.y); v.w = pkbf(v1.z, v1.w);
        ((uint4*)Wp)[s] = v;

        const float4* src2 = (const float4*)(Wm2 + (size_t)d * DEC + k);
        float4 w0 = src2[0], w1 = src2[1];
        uint4 w;
        w.x = pkbf(w0.x, w0.y); w.y = pkbf(w0.z, w0.w);
        w.z = pkbf(w1.x, w1.y); w.w = pkbf(w1.z, w1.w);
        ((uint4*)Wp2)[s] = w;
    } else if (bid < 128 + 4096) {
        // one bias output per wave: gw in [0,16384)
        int gw = (bid - 128) * 4 + (tid >> 6);
        int lane = tid & 63;
        int mat = gw >> 13;                 // 0: bias1 (Wd,Wt), 1: bias2 (Wd2,Wt2)
        int rem = gw & 8191;
        int bb = rem >> 9;                  // 0..15
        int d = rem & 511;                  // 0..511

        const float* wrow = (mat ? Wd2 : Wd) + (size_t)d * DEC;
        const float* drow = dec + (size_t)bb * DEC;
        float4 a0 = ((const float4*)wrow)[lane * 2];
        float4 a1 = ((const float4*)wrow)[lane * 2 + 1];
        float4 x0 = ((const float4*)drow)[lane * 2];
        float4 x1 = ((const float4*)drow)[lane * 2 + 1];
        float acc = a0.x * x0.x;
        acc = fmaf(a0.y, x0.y, acc);
        acc = fmaf(a0.z, x0.z, acc);
        acc = fmaf(a0.w, x0.w, acc);
        acc = fmaf(a1.x, x1.x, acc);
        acc = fmaf(a1.y, x1.y, acc);
        acc = fmaf(a1.z, x1.z, acc);
        acc = fmaf(a1.w, x1.w, acc);
        const float* trow = (mat ? Wt2 : Wt) + (size_t)d * TOPN;
        if (lane < TOPN) acc = fmaf(trow[lane], topic[bb * TOPN + lane], acc);
#pragma unroll
        for (int o = 1; o <= 32; o <<= 1) acc += __shfl_xor(acc, o);
        if (lane == 0) (mat ? bias2 : bias1)[bb * DEC + d] = acc;
    } else {
        // zero ctx accumulator region of d_out (8192 floats), 4 blocks
        int i = (bid - (128 + 4096)) * 256 + tid;   // 0..1023
        float4 z = {0.f, 0.f, 0.f, 0.f};
        ((float4*)ctx_out)[i * 2] = z;
        ((float4*)ctx_out)[i * 2 + 1] = z;
    }
}

// ============ fused score kernel (R7): M=128/block, K-quarter staged pipeline ============
// Block = 128 rows (word mode: exactly one (b,q)); 512 threads = 8 waves.
// Wave w owns d = w*64..+63 (nt = {2w,2w+1}), all 128 rows: acc[8] (4 row-groups x 2 nt).
// A (128x512 fp32 -> bf16) staged into LDS in 4 K-quarters (64 KB each), loads issued
// 2 quarters ahead, lgkm-only barriers; compute never drains vmcnt.
// Quarter order rotated by (bid&3): de-lockstep chip-wide reads of the shared 1MB weights.
// B: 2 uint4/step from L2, 4-step register ring (static indices).
// mode 0 = word: + doc-softmax, word-softmax, rescale out, ctx (fp32 X re-read, L3-hot).
// mode 1 = doc: write raw scores only (per-row-group batch index).
__global__ __launch_bounds__(512, 2) void score_fused_kernel(
    const float* __restrict__ X,             // [rows][512] fp32
    const unsigned short* __restrict__ Wp_,  // permuted bf16 weights (512 KB)
    const float* __restrict__ Wv_,           // [512]
    const float* __restrict__ bias_,         // [16][512]
    const float* __restrict__ doc_scores,    // [512] (word mode)
    const int* __restrict__ doc_mask,        // [512] (word mode)
    const int* __restrict__ word_mask,       // [65536] (word mode)
    float* __restrict__ rescaled_out,        // d_out + 8192 (word mode)
    float* __restrict__ ctx_out,             // d_out [16][512] (word mode, atomic)
    float* __restrict__ scores_out,          // doc mode raw scores
    int mode)
{
    __shared__ __align__(16) char lsA[128 * 1040];   // 133120 B: full A tile bf16, 16B row pad
    __shared__ float red[8][128];
    __shared__ float sS[128];
    __shared__ float rmax2[2], rsum2[2];
    __shared__ float s_dattn;
    __shared__ __align__(16) float4 part[3 * 128];

    const int tid = threadIdx.x;
    const int lane = tid & 63;
    const int w = tid >> 6;            // 0..7: d-slice
    const int bid = blockIdx.x;
    const int r0 = bid * 128;
    const int col = lane & 31;
    const int h = lane >> 5;

    // quarter rotation
    const int q0 = bid & 3;
    const int Q[4] = { q0, (q0 + 1) & 3, (q0 + 2) & 3, (q0 + 3) & 3 };
#define CH_AT(f) (Q[(f) >> 3] * 8 + ((f) & 7))

    // ---- staging map: thread covers f4col = qq*32 + (tid&31), rows (tid>>5) + 16*i ----
    const int scol = tid & 31;
    const int srow0 = tid >> 5;        // 0..15
    const float4* Xbase = (const float4*)X + (size_t)(r0 + srow0) * 128 + scol;
    char* const wbase = lsA + (size_t)srow0 * 1040 + scol * 8;

#define ISSUEQ(buf, qq) { _Pragma("unroll") for (int i = 0; i < 8; ++i) \
        buf[i] = Xbase[(size_t)(16 * i) * 128 + (qq) * 32]; }
#define WRITEQ(buf, qq) { _Pragma("unroll") for (int i = 0; i < 8; ++i) { \
        uint2 ww; ww.x = pkbf(buf[i].x, buf[i].y); ww.y = pkbf(buf[i].z, buf[i].w); \
        *(uint2*)(wbase + (size_t)(16 * i) * 1040 + (qq) * 256) = ww; } }
#define LGKMBAR { asm volatile("s_waitcnt lgkmcnt(0)" ::: "memory"); \
                  __builtin_amdgcn_s_barrier(); asm volatile("" ::: "memory"); }
#define MFMA(a, bb, c) __builtin_amdgcn_mfma_f32_32x32x16_bf16(a, bb, c, 0, 0, 0)

    // ---- B addressing: slot(chunk c, lane) = c*1024 + w*128 + lane (+64 for nt odd) ----
    const uint4* Bq4 = (const uint4*)Wp_;
    const int vB = w * 128 + lane;

    // ---- A fragment row bases (rg = row group 0..3; row = rg*32 + col, k-half h) ----
    const char* const aR0 = lsA + (size_t)col * 1040 + h * 16;
    const char* const aR1 = aR0 + 32 * 1040;
    const char* const aR2 = aR0 + 64 * 1040;
    const char* const aR3 = aR0 + 96 * 1040;

    f32x16 acc[8];   // [rg*2 + nt]
#pragma unroll
    for (int t = 0; t < 8; ++t)
        acc[t] = (f32x16){0.f,0.f,0.f,0.f, 0.f,0.f,0.f,0.f, 0.f,0.f,0.f,0.f, 0.f,0.f,0.f,0.f};

    uint4 rb[4][2];

#define STEP(f, a0q, a1q, a2q, a3q) { \
        union { uint4 u; short8 s8; } b0{rb[(f) & 3][0]}, b1{rb[(f) & 3][1]}; \
        if ((f) + 4 < 32) { \
            const int cn_ = CH_AT((f) + 4); \
            rb[(f) & 3][0] = Bq4[(size_t)cn_ * 1024 + vB]; \
            rb[(f) & 3][1] = Bq4[(size_t)cn_ * 1024 + vB + 64]; \
        } \
        short8 a0 = *(const short8*)((a0q) + ((f) & 7) * 32); \
        short8 a1 = *(const short8*)((a1q) + ((f) & 7) * 32); \
        short8 a2 = *(const short8*)((a2q) + ((f) & 7) * 32); \
        short8 a3 = *(const short8*)((a3q) + ((f) & 7) * 32); \
        acc[0] = MFMA(a0, b0.s8, acc[0]); \
        acc[1] = MFMA(a0, b1.s8, acc[1]); \
        acc[2] = MFMA(a1, b0.s8, acc[2]); \
        acc[3] = MFMA(a1, b1.s8, acc[3]); \
        acc[4] = MFMA(a2, b0.s8, acc[4]); \
        acc[5] = MFMA(a2, b1.s8, acc[5]); \
        acc[6] = MFMA(a3, b0.s8, acc[6]); \
        acc[7] = MFMA(a3, b1.s8, acc[7]); }

#define QUARTER(j, f0) { \
        const int qo_ = Q[j] * 256; \
        const char* a0q = aR0 + qo_; const char* a1q = aR1 + qo_; \
        const char* a2q = aR2 + qo_; const char* a3q = aR3 + qo_; \
        STEP((f0) + 0, a0q, a1q, a2q, a3q) STEP((f0) + 1, a0q, a1q, a2q, a3q) \
        STEP((f0) + 2, a0q, a1q, a2q, a3q) STEP((f0) + 3, a0q, a1q, a2q, a3q) \
        STEP((f0) + 4, a0q, a1q, a2q, a3q) STEP((f0) + 5, a0q, a1q, a2q, a3q) \
        STEP((f0) + 6, a0q, a1q, a2q, a3q) STEP((f0) + 7, a0q, a1q, a2q, a3q) }

    // ---- staged pipeline ----
    float4 sb0[8], sb1[8];
    ISSUEQ(sb0, Q[0]);
    ISSUEQ(sb1, Q[1]);

    // doc softmax for this block's (b,q) — overlaps staging load latency
    if (mode == 0 && tid < 32) {
        int b_ = bid >> 5;
        int di = b_ * 32 + tid;
        float dsv = doc_scores[di];
        if (doc_mask[di] == 0) dsv = -INFINITY;
        float mx = dsv;
#pragma unroll
        for (int o = 1; o <= 16; o <<= 1) mx = fmaxf(mx, __shfl_xor(mx, o));
        float e = __expf(dsv - mx);
        float sum = e;
#pragma unroll
        for (int o = 1; o <= 16; o <<= 1) sum += __shfl_xor(sum, o);
        if (tid == (bid & 31)) s_dattn = e / sum;
    }

    WRITEQ(sb0, Q[0]);
    // ring prologue: chunks CH(0..3) in flight across the barrier
#pragma unroll
    for (int f = 0; f < 4; ++f) {
        const int c_ = CH_AT(f);
        rb[f][0] = Bq4[(size_t)c_ * 1024 + vB];
        rb[f][1] = Bq4[(size_t)c_ * 1024 + vB + 64];
    }
    LGKMBAR;

    ISSUEQ(sb0, Q[2]);
    QUARTER(0, 0);
    WRITEQ(sb1, Q[1]);
    LGKMBAR;

    ISSUEQ(sb1, Q[3]);
    QUARTER(1, 8);
    WRITEQ(sb0, Q[2]);
    LGKMBAR;

    QUARTER(2, 16);
    WRITEQ(sb1, Q[3]);
    LGKMBAR;

    QUARTER(3, 24);

    // ---- epilogue: tanh + Wv partial over this wave's 64 d ----
    // C/D layout (32x32, HW-verified): col = lane&31, row_in = (r&3)+8*(r>>2)+4*h
    {
        const int d0 = w * 64 + col;
        const float wv0 = Wv_[d0], wv1 = Wv_[d0 + 32];
#pragma unroll
        for (int rg = 0; rg < 4; ++rg) {
            const int brg = mode ? (bid * 4 + rg) : (bid >> 5);
            const float bs0 = bias_[brg * DEC + d0];
            const float bs1 = bias_[brg * DEC + d0 + 32];
#pragma unroll
            for (int r = 0; r < 16; ++r) {
                float val = fmaf(wv0, fast_tanh(acc[rg * 2 + 0][r] + bs0),
                                 wv1 * fast_tanh(acc[rg * 2 + 1][r] + bs1));
                val += __shfl_xor(val, 16);
                val += __shfl_xor(val, 8);
                val += __shfl_xor(val, 4);
                val += __shfl_xor(val, 2);
                val += __shfl_xor(val, 1);
                if (col == r) {
                    int row_in = (r & 3) + 8 * (r >> 2) + 4 * h;
                    red[w][rg * 32 + row_in] = val;
                }
            }
        }
    }
    __syncthreads();

    if (mode) {
        if (tid < 128)
            scores_out[r0 + tid] = red[0][tid] + red[1][tid] + red[2][tid] + red[3][tid]
                                 + red[4][tid] + red[5][tid] + red[6][tid] + red[7][tid];
        return;
    }

    // ---- word softmax over 128 rows (threads 0..127) ----
    float e = 0.f, sv = 0.f;
    if (tid < 128) {
        sv = red[0][tid] + red[1][tid] + red[2][tid] + red[3][tid]
           + red[4][tid] + red[5][tid] + red[6][tid] + red[7][tid];
        if (word_mask[r0 + tid] == 0) sv = -INFINITY;
        float mx = sv;
#pragma unroll
        for (int o = 1; o <= 32; o <<= 1) mx = fmaxf(mx, __shfl_xor(mx, o));
        if (lane == 0) rmax2[w] = mx;
    }
    __syncthreads();
    if (tid < 128) {
        float mx = fmaxf(rmax2[0], rmax2[1]);
        e = __expf(sv - mx);
        float sum = e;
#pragma unroll
        for (int o = 1; o <= 32; o <<= 1) sum += __shfl_xor(sum, o);
        if (lane == 0) rsum2[w] = sum;
    }
    __syncthreads();
    if (tid < 128) {
        float sum = rsum2[0] + rsum2[1];
        float resc = s_dattn * (e / sum);
        sS[tid] = resc;
        rescaled_out[r0 + tid] = resc;
    }
    __syncthreads();

    // ---- context partial (fp32 X re-read, L3-hot) + atomic accumulate ----
    const int b_ = bid >> 5;
    const int hh = tid >> 7;          // 0..3: 32-row group
    const int m4 = tid & 127;         // float4 index in m
    const float4* Xr = (const float4*)X + (size_t)r0 * 128 + (size_t)hh * 32 * 128 + m4;
    float4 a = {0.f, 0.f, 0.f, 0.f};
#pragma unroll 8
    for (int i = 0; i < 32; ++i) {
        float rr = sS[hh * 32 + i];
        float4 v = Xr[(size_t)i * 128];
        a.x = fmaf(rr, v.x, a.x);
        a.y = fmaf(rr, v.y, a.y);
        a.z = fmaf(rr, v.z, a.z);
        a.w = fmaf(rr, v.w, a.w);
    }
    if (hh) part[(hh - 1) * 128 + m4] = a;
    __syncthreads();
    if (hh == 0) {
        float4 p0 = part[m4], p1 = part[128 + m4], p2 = part[256 + m4];
        a.x += p0.x + p1.x + p2.x;
        a.y += p0.y + p1.y + p2.y;
        a.z += p0.z + p1.z + p2.z;
        a.w += p0.w + p1.w + p2.w;
        float* dst = ctx_out + (size_t)b_ * MEM + m4 * 4;
        atomicAdd(dst + 0, a.x);
        atomicAdd(dst + 1, a.y);
        atomicAdd(dst + 2, a.z);
        atomicAdd(dst + 3, a.w);
    }
}

extern "C" void kernel_launch(void* const* d_in, const int* in_sizes, int n_in,
                              void* d_out, int out_size, void* d_ws, size_t ws_size,
                              hipStream_t stream) {
    const float* decoder_state = (const float*)d_in[0];
    const float* doc_memory    = (const float*)d_in[1];
    const float* word_memory   = (const float*)d_in[2];
    const float* topic_dist    = (const float*)d_in[3];
    const int*   doc_mask      = (const int*)d_in[4];
    const int*   word_mask     = (const int*)d_in[5];
    const float* Wv  = (const float*)d_in[6];
    const float* Wd  = (const float*)d_in[7];
    const float* Wt  = (const float*)d_in[8];
    const float* Wm  = (const float*)d_in[9];
    const float* Wv2 = (const float*)d_in[10];
    const float* Wd2 = (const float*)d_in[11];
    const float* Wt2 = (const float*)d_in[12];
    const float* Wm2 = (const float*)d_in[13];

    float* ws = (float*)d_ws;
    unsigned short* Wp  = (unsigned short*)(ws + WS_WP);
    unsigned short* Wp2 = (unsigned short*)(ws + WS_WP2);
    float* bias1       = ws + WS_BIAS1;
    float* bias2       = ws + WS_BIAS2;
    float* doc_scores  = ws + WS_DOCSC;

    float* ctx_out      = (float*)d_out;                 // [16][512]
    float* rescaled_out = (float*)d_out + BATCH * MEM;   // [16][32][128]

    setup_kernel<<<128 + 4096 + 4, 256, 0, stream>>>(Wm, Wm2, Wp, Wp2,
                                                     decoder_state, topic_dist,
                                                     Wd, Wt, Wd2, Wt2, bias1, bias2, ctx_out);
    // doc scores: 512 doc rows = 4 blocks of 128 (mode 1)
    score_fused_kernel<<<4, 512, 0, stream>>>(doc_memory, Wp2, Wv2, bias2,
                                              nullptr, nullptr, nullptr,
                                              nullptr, nullptr, doc_scores, 1);
    // word: 512 blocks, one (b,q) each (mode 0), fully fused through ctx
    score_fused_kernel<<<NBQ, 512, 0, stream>>>(word_memory, Wp, Wv, bias1,
                                                doc_scores, doc_mask, word_mask,
                                                rescaled_out, ctx_out, nullptr, 0);
}